// Round 13
// baseline (116.052 us; speedup 1.0000x reference)
//
#include <hip/hip_runtime.h>
#include <stdint.h>

#define B_ 8
#define C_ 256
#define O_ 256
#define HW_ 4096
#define RS 2560  // s_x row stride in halves (5120 B, 16B-aligned — do NOT pad, breaks b128)

typedef _Float16 f16x8 __attribute__((ext_vector_type(8)));
typedef __attribute__((ext_vector_type(4))) float f32x4;

// ---------- prep: x (NCHW f32) -> xT (NHWC fp16, relu), LDS-transposed writes ----------
__global__ __launch_bounds__(256) void k_nhwc2(const float* __restrict__ x,
                                               _Float16* __restrict__ xT) {
    int bh = blockIdx.x;
    int b = bh & 7, h = bh >> 3;
    int tid = threadIdx.x;
    __shared__ __align__(16) _Float16 s_t[64 * 72];
    int px = tid & 63, wg = tid >> 6;
    int px3 = tid >> 3, o8 = tid & 7;
#pragma unroll
    for (int half = 0; half < 4; ++half) {
        int c0 = half * 64;
        f16x8 va, vb;
#pragma unroll
        for (int j = 0; j < 8; ++j) {
            float f0 = x[((size_t)(b * C_ + c0 + wg * 16 + j)) * HW_ + h * 64 + px];
            float f1 = x[((size_t)(b * C_ + c0 + wg * 16 + 8 + j)) * HW_ + h * 64 + px];
            va[j] = (_Float16)fmaxf(f0, 0.f);
            vb[j] = (_Float16)fmaxf(f1, 0.f);
        }
        if (half) __syncthreads();
        *reinterpret_cast<f16x8*>(&s_t[px * 72 + wg * 16]) = va;
        *reinterpret_cast<f16x8*>(&s_t[px * 72 + wg * 16 + 8]) = vb;
        __syncthreads();
#pragma unroll
        for (int it = 0; it < 2; ++it) {
            int p = it * 32 + px3;
            f16x8 w = *reinterpret_cast<const f16x8*>(&s_t[p * 72 + o8 * 8]);
            *reinterpret_cast<f16x8*>(
                &xT[((size_t)((b * 64 + h) * 64 + p)) * C_ + c0 + o8 * 8]) = w;
        }
    }
}

// ---------- prep: w_def -> fp16 MFMA A-frags [k2][q8][mfg16][lane64][8] ----------
__global__ void k_prep_wdef(const float* __restrict__ w_def, _Float16* __restrict__ wfrag) {
    int idx = blockIdx.x * 256 + threadIdx.x;
    if (idx >= 9 * 8 * 16 * 64) return;
    int lane = idx & 63;
    int mfg = (idx >> 6) & 15;
    int ccc = (idx >> 10) & 7;
    int k2 = idx >> 13;
    int o = mfg * 16 + (lane & 15);
    int cb = ccc * 32 + (lane >> 4) * 8;
    f16x8 pk;
#pragma unroll
    for (int j = 0; j < 8; ++j)
        pk[j] = (_Float16)w_def[(size_t)(o * C_ + cb + j) * 9 + k2];
    *reinterpret_cast<f16x8*>(wfrag + (size_t)idx * 8) = pk;
}

// ---------- prep: w_off -> fp16 MFMA A-frags (M pad 18->32) ----------
__global__ void k_prep_woffrag(const float* __restrict__ w_off, _Float16* __restrict__ wfr) {
    int idx = blockIdx.x * 256 + threadIdx.x;
    if (idx >= 9 * 8 * 2 * 64) return;
    int lane = idx & 63;
    int mfg = (idx >> 6) & 1;
    int ccc = (idx >> 7) & 7;
    int k2 = idx >> 10;
    int o = mfg * 16 + (lane & 15);
    int cb = ccc * 32 + (lane >> 4) * 8;
    f16x8 pk;
#pragma unroll
    for (int j = 0; j < 8; ++j)
        pk[j] = (o < 18) ? (_Float16)w_off[(size_t)(o * C_ + cb + j) * 9 + k2] : (_Float16)0.f;
    *reinterpret_cast<f16x8*>(wfr + (size_t)idx * 8) = pk;
}

// ---------- offset conv via MFMA, no LDS ----------
__global__ __launch_bounds__(256) void k_offconv4(const _Float16* __restrict__ xT,
                                                  const _Float16* __restrict__ wofr,
                                                  const float* __restrict__ b_off,
                                                  float* __restrict__ offs) {
    int bh = blockIdx.x;
    int b = bh & 7, h = bh >> 3;
    int tid = threadIdx.x, lane = tid & 63, wm = tid >> 6;
    int px = wm * 16 + (lane & 15);
    int chl = (lane >> 4) * 8;
    f32x4 acc0 = (f32x4){0.f, 0.f, 0.f, 0.f};
    f32x4 acc1 = (f32x4){0.f, 0.f, 0.f, 0.f};
    const _Float16* xb = xT + (size_t)b * HW_ * C_;
    for (int k2 = 0; k2 < 9; ++k2) {
        int y = h + k2 / 3 - 1;
        int xs = px + k2 % 3 - 1;
        bool v = ((unsigned)y < 64u) && ((unsigned)xs < 64u);
        int yc = y < 0 ? 0 : (y > 63 ? 63 : y);
        int xc = xs < 0 ? 0 : (xs > 63 ? 63 : xs);
        const _Float16* xp = xb + (size_t)(yc * 64 + xc) * C_ + chl;
#pragma unroll
        for (int q = 0; q < 8; ++q) {
            f16x8 bf = *reinterpret_cast<const f16x8*>(xp + q * 32);
            if (!v) bf = (f16x8)(_Float16)0.f;
            const f16x8* wp = reinterpret_cast<const f16x8*>(wofr) +
                              (size_t)((k2 * 8 + q) * 2) * 64 + lane;
            acc0 = __builtin_amdgcn_mfma_f32_16x16x32_f16(wp[0], bf, acc0, 0, 0, 0);
            acc1 = __builtin_amdgcn_mfma_f32_16x16x32_f16(wp[64], bf, acc1, 0, 0, 0);
        }
    }
#pragma unroll
    for (int r = 0; r < 4; ++r) {
        int oc = (lane >> 4) * 4 + r;
        offs[(((size_t)b * 18 + oc) * 64 + h) * 64 + px] = acc0[r] + b_off[oc];
    }
#pragma unroll
    for (int r = 0; r < 4; ++r) {
        int oc = 16 + (lane >> 4) * 4 + r;
        if (oc < 18)
            offs[(((size_t)b * 18 + oc) * 64 + h) * 64 + px] = acc1[r] + b_off[oc];
    }
}

// ---------- deform v13: flat 72-step loop, 2-deep pack pipeline, counted lgkm ----------
// s_samp triple-buffered; s_x double-buffered 5-row windows; one barrier/step.
__global__ __launch_bounds__(256, 2) void k_deform13(const _Float16* __restrict__ xT,
                                                     const _Float16* __restrict__ wfrag,
                                                     const float* __restrict__ offs,
                                                     float* __restrict__ out) {
    int blk = blockIdx.x;
    int b = blk & 7, h = blk >> 3;
    int tid = threadIdx.x, lane = tid & 63, wm = tid >> 6;
    int gp = tid & 63, gq = tid >> 6;

    __shared__ uint4 s_geo[576];
    __shared__ __align__(16) _Float16 s_x[2][5 * RS];
    __shared__ __align__(16) _Float16 s_samp[3][64 * 40];

    const _Float16* xb = xT + (size_t)b * HW_ * C_;

    int spx = tid >> 2, so = tid & 3;
    f16x8 st[5];
#define STAGE_LOAD(CQ)                                                             \
    {                                                                              \
        _Pragma("unroll") for (int r = 0; r < 5; ++r)                              \
        {                                                                          \
            int yr = h - 2 + r;                                                    \
            yr = yr < 0 ? 0 : (yr > 63 ? 63 : yr);                                 \
            st[r] = *reinterpret_cast<const f16x8*>(                               \
                xb + (size_t)(yr * 64 + spx) * C_ + (CQ) * 32 + so * 8);           \
        }                                                                          \
    }
#define STAGE_WRITE(PAR)                                                           \
    {                                                                              \
        _Pragma("unroll") for (int r = 0; r < 5; ++r)                              \
            *reinterpret_cast<f16x8*>(&s_x[PAR][r * RS + spx * 40 + so * 8]) = st[r]; \
    }

    STAGE_LOAD(0);

    // ---- geometry (once per block), 5-row window flag in [0,3] ----
    for (int idx = tid; idx < 576; idx += 256) {
        int k2 = idx >> 6, p = idx & 63;
        float dy = offs[(((size_t)b * 18 + k2 * 2 + 0) * 64 + h) * 64 + p];
        float dx = offs[(((size_t)b * 18 + k2 * 2 + 1) * 64 + h) * 64 + p];
        float py = (float)(h - 1 + k2 / 3) + dy;
        float pxx = (float)(p - 1 + k2 % 3) + dx;
        float y0f = floorf(py), x0f = floorf(pxx);
        float wy = py - y0f, wx = pxx - x0f;
        int y0 = (int)y0f, x0 = (int)x0f;
        float w00 = (1.f - wy) * (1.f - wx), w01 = (1.f - wy) * wx;
        float w10 = wy * (1.f - wx), w11 = wy * wx;
        bool vy0 = (unsigned)y0 < 64u, vy1 = (unsigned)(y0 + 1) < 64u;
        bool vx0 = (unsigned)x0 < 64u, vx1 = (unsigned)(x0 + 1) < 64u;
        if (!(vy0 && vx0)) w00 = 0.f;
        if (!(vy0 && vx1)) w01 = 0.f;
        if (!(vy1 && vx0)) w10 = 0.f;
        if (!(vy1 && vx1)) w11 = 0.f;
        union { _Float16 h2[2]; unsigned u; } p01, p23;
        p01.h2[0] = (_Float16)w00; p01.h2[1] = (_Float16)w01;
        p23.h2[0] = (_Float16)w10; p23.h2[1] = (_Float16)w11;
        int x0c = x0 < 0 ? 0 : (x0 > 63 ? 63 : x0);
        int x1c = (x0 + 1) < 0 ? 0 : ((x0 + 1) > 63 ? 63 : (x0 + 1));
        int y0c = y0 < 0 ? 0 : (y0 > 63 ? 63 : y0);
        int y1c = (y0 + 1) < 0 ? 0 : ((y0 + 1) > 63 ? 63 : (y0 + 1));
        int ry0 = y0 - (h - 2);
        unsigned flag = (ry0 >= 0 && ry0 <= 3) ? (unsigned)ry0 : 255u;
        uint4 g;
        g.x = p01.u;
        g.y = p23.u;
        g.z = (unsigned)x0c | ((unsigned)x1c << 16);
        g.w = (unsigned)y0c | ((unsigned)y1c << 8) | (flag << 16);
        s_geo[idx] = g;
    }

    STAGE_WRITE(0);
    asm volatile("s_waitcnt lgkmcnt(0)" ::: "memory");
    __builtin_amdgcn_s_barrier();

    f32x4 acc[4][4];
#pragma unroll
    for (int i = 0; i < 4; ++i)
#pragma unroll
        for (int j = 0; j < 4; ++j) acc[i][j] = (f32x4){0.f, 0.f, 0.f, 0.f};

#define LOADA(DST, T)                                                              \
    {                                                                              \
        const f16x8* wf = reinterpret_cast<const f16x8*>(wfrag) +                  \
                          ((size_t)(T) * 16 + wm * 4) * 64 + lane;                 \
        _Pragma("unroll") for (int mf = 0; mf < 4; ++mf) DST[mf] = wf[mf * 64];    \
    }

#define PACKSTEP(T, BUF)                                                           \
    {                                                                              \
        int t_ = (T);                                                              \
        int cqt_ = t_ / 9, k2t_ = t_ - cqt_ * 9;                                   \
        uint4 gg = s_geo[k2t_ * 64 + gp];                                          \
        union { unsigned u; _Float16 h2[2]; } p01, p23;                            \
        p01.u = gg.x; p23.u = gg.y;                                                \
        int x0c = gg.z & 0xFFFF, x1c = gg.z >> 16;                                 \
        int flag = gg.w >> 16;                                                     \
        f16x8 c00, c01, c10, c11;                                                  \
        if (flag <= 3) {                                                           \
            const _Float16* b0 = &s_x[cqt_ & 1][flag * RS + gq * 8];               \
            c00 = *reinterpret_cast<const f16x8*>(b0 + x0c * 40);                  \
            c01 = *reinterpret_cast<const f16x8*>(b0 + x1c * 40);                  \
            c10 = *reinterpret_cast<const f16x8*>(b0 + RS + x0c * 40);             \
            c11 = *reinterpret_cast<const f16x8*>(b0 + RS + x1c * 40);             \
        } else {                                                                   \
            int y0c = gg.w & 0xFF, y1c = (gg.w >> 8) & 0xFF;                       \
            const _Float16* gb = xb + cqt_ * 32 + gq * 8;                          \
            c00 = *reinterpret_cast<const f16x8*>(gb + (size_t)(y0c * 64 + x0c) * C_); \
            c01 = *reinterpret_cast<const f16x8*>(gb + (size_t)(y0c * 64 + x1c) * C_); \
            c10 = *reinterpret_cast<const f16x8*>(gb + (size_t)(y1c * 64 + x0c) * C_); \
            c11 = *reinterpret_cast<const f16x8*>(gb + (size_t)(y1c * 64 + x1c) * C_); \
        }                                                                          \
        f16x8 pk = c00 * p01.h2[0] + c01 * p01.h2[1] + c10 * p23.h2[0] + c11 * p23.h2[1]; \
        *reinterpret_cast<f16x8*>(&s_samp[BUF][gp * 40 + gq * 8]) = pk;            \
    }

    f16x8 Ac[4], An[4];

    // prologue: pack steps 0,1; load A for step 0
    PACKSTEP(0, 0);
    PACKSTEP(1, 1);
    LOADA(Ac, 0);
#pragma unroll
    for (int mf = 0; mf < 4; ++mf) An[mf] = Ac[mf];
    asm volatile("s_waitcnt lgkmcnt(0)" ::: "memory");
    __builtin_amdgcn_s_barrier();

#define STEP(S_, BUFJ, PBUF, LASTWAIT)                                             \
    {                                                                              \
        int s_ = (S_);                                                             \
        int cq_ = s_ / 9, k2_ = s_ - cq_ * 9;                                      \
        f16x8 bfr[4];                                                              \
        _Pragma("unroll") for (int nf = 0; nf < 4; ++nf)                           \
        {                                                                          \
            int n = nf * 16 + (lane & 15);                                         \
            bfr[nf] = *reinterpret_cast<const f16x8*>(                             \
                &s_samp[BUFJ][n * 40 + (lane >> 4) * 8]);                          \
        }                                                                          \
        if (k2_ == 0 && cq_ < 7) STAGE_LOAD(cq_ + 1);                              \
        if (k2_ == 4 && cq_ < 7) STAGE_WRITE((cq_ + 1) & 1);                       \
        if (s_ + 2 < 72) PACKSTEP(s_ + 2, PBUF);                                   \
        if (s_ + 1 < 72) {                                                         \
            int s1 = s_ + 1;                                                       \
            int c1 = s1 / 9;                                                       \
            LOADA(An, (s1 - c1 * 9) * 8 + c1);                                     \
        }                                                                          \
        _Pragma("unroll") for (int mf = 0; mf < 4; ++mf)                           \
            _Pragma("unroll") for (int nf = 0; nf < 4; ++nf)                       \
                acc[mf][nf] = __builtin_amdgcn_mfma_f32_16x16x32_f16(              \
                    Ac[mf], bfr[nf], acc[mf][nf], 0, 0, 0);                        \
        if (s_ + 1 < 72) {                                                         \
            _Pragma("unroll") for (int mf = 0; mf < 4; ++mf) Ac[mf] = An[mf];      \
        }                                                                          \
        if (LASTWAIT) {                                                            \
            asm volatile("s_waitcnt lgkmcnt(0)" ::: "memory");                     \
        } else {                                                                   \
            asm volatile("s_waitcnt lgkmcnt(1)" ::: "memory");                     \
        }                                                                          \
        __builtin_amdgcn_s_barrier();                                              \
        __builtin_amdgcn_sched_barrier(0);                                         \
    }

#pragma unroll 1
    for (int ss = 0; ss < 23; ++ss) {
        int s0 = ss * 3;
        STEP(s0 + 0, 0, 2, 0);
        STEP(s0 + 1, 1, 0, 0);
        STEP(s0 + 2, 2, 1, 0);
    }
    STEP(69, 0, 2, 1);
    STEP(70, 1, 0, 1);
    STEP(71, 2, 1, 1);

    float* op = out + (size_t)b * O_ * HW_ + h * 64;
#pragma unroll
    for (int mf = 0; mf < 4; ++mf)
#pragma unroll
        for (int nf = 0; nf < 4; ++nf)
#pragma unroll
            for (int r = 0; r < 4; ++r) {
                int o = wm * 64 + mf * 16 + (lane >> 4) * 4 + r;
                int w = nf * 16 + (lane & 15);
                op[(size_t)o * HW_ + w] = acc[mf][nf][r];
            }
}

extern "C" void kernel_launch(void* const* d_in, const int* in_sizes, int n_in,
                              void* d_out, int out_size, void* d_ws, size_t ws_size,
                              hipStream_t stream) {
    const float* x = (const float*)d_in[0];
    const float* w_off = (const float*)d_in[1];
    const float* b_off = (const float*)d_in[2];
    const float* w_def = (const float*)d_in[3];
    float* out = (float*)d_out;
    char* ws = (char*)d_ws;

    float* offs = (float*)ws;                                            // 2,359,296 B
    _Float16* xT = (_Float16*)(ws + 2359296);                            // 16,777,216 B
    _Float16* wfrag = (_Float16*)(ws + 2359296 + 16777216);              // 1,179,648 B
    _Float16* wofr = (_Float16*)(ws + 2359296 + 16777216 + 1179648);     // 147,456 B

    k_nhwc2<<<512, 256, 0, stream>>>(x, xT);
    k_prep_wdef<<<288, 256, 0, stream>>>(w_def, wfrag);
    k_prep_woffrag<<<36, 256, 0, stream>>>(w_off, wofr);
    k_offconv4<<<512, 256, 0, stream>>>(xT, wofr, b_off, offs);
    k_deform13<<<512, 256, 0, stream>>>(xT, wfrag, offs, out);
}

// Round 14
// 106.391 us; speedup vs baseline: 1.0908x; 1.0908x over previous
//
#include <hip/hip_runtime.h>
#include <stdint.h>

#define B_ 8
#define C_ 256
#define O_ 256
#define HW_ 4096
#define RS 2560  // s_x row stride in halves (5120 B, 16B-aligned — do NOT pad, breaks b128)

typedef _Float16 f16x8 __attribute__((ext_vector_type(8)));
typedef __attribute__((ext_vector_type(4))) float f32x4;

// ---------- prep: x (NCHW f32) -> xT (NHWC fp16, relu), LDS-transposed writes ----------
__global__ __launch_bounds__(256) void k_nhwc2(const float* __restrict__ x,
                                               _Float16* __restrict__ xT) {
    int bh = blockIdx.x;
    int b = bh & 7, h = bh >> 3;
    int tid = threadIdx.x;
    __shared__ __align__(16) _Float16 s_t[64 * 72];
    int px = tid & 63, wg = tid >> 6;
    int px3 = tid >> 3, o8 = tid & 7;
#pragma unroll
    for (int half = 0; half < 4; ++half) {
        int c0 = half * 64;
        f16x8 va, vb;
#pragma unroll
        for (int j = 0; j < 8; ++j) {
            float f0 = x[((size_t)(b * C_ + c0 + wg * 16 + j)) * HW_ + h * 64 + px];
            float f1 = x[((size_t)(b * C_ + c0 + wg * 16 + 8 + j)) * HW_ + h * 64 + px];
            va[j] = (_Float16)fmaxf(f0, 0.f);
            vb[j] = (_Float16)fmaxf(f1, 0.f);
        }
        if (half) __syncthreads();
        *reinterpret_cast<f16x8*>(&s_t[px * 72 + wg * 16]) = va;
        *reinterpret_cast<f16x8*>(&s_t[px * 72 + wg * 16 + 8]) = vb;
        __syncthreads();
#pragma unroll
        for (int it = 0; it < 2; ++it) {
            int p = it * 32 + px3;
            f16x8 w = *reinterpret_cast<const f16x8*>(&s_t[p * 72 + o8 * 8]);
            *reinterpret_cast<f16x8*>(
                &xT[((size_t)((b * 64 + h) * 64 + p)) * C_ + c0 + o8 * 8]) = w;
        }
    }
}

// ---------- prep: w_def -> fp16 MFMA A-frags [k2][q8][mfg16][lane64][8] ----------
__global__ void k_prep_wdef(const float* __restrict__ w_def, _Float16* __restrict__ wfrag) {
    int idx = blockIdx.x * 256 + threadIdx.x;
    if (idx >= 9 * 8 * 16 * 64) return;
    int lane = idx & 63;
    int mfg = (idx >> 6) & 15;
    int ccc = (idx >> 10) & 7;
    int k2 = idx >> 13;
    int o = mfg * 16 + (lane & 15);
    int cb = ccc * 32 + (lane >> 4) * 8;
    f16x8 pk;
#pragma unroll
    for (int j = 0; j < 8; ++j)
        pk[j] = (_Float16)w_def[(size_t)(o * C_ + cb + j) * 9 + k2];
    *reinterpret_cast<f16x8*>(wfrag + (size_t)idx * 8) = pk;
}

// ---------- prep: w_off -> fp16 MFMA A-frags (M pad 18->32) ----------
__global__ void k_prep_woffrag(const float* __restrict__ w_off, _Float16* __restrict__ wfr) {
    int idx = blockIdx.x * 256 + threadIdx.x;
    if (idx >= 9 * 8 * 2 * 64) return;
    int lane = idx & 63;
    int mfg = (idx >> 6) & 1;
    int ccc = (idx >> 7) & 7;
    int k2 = idx >> 10;
    int o = mfg * 16 + (lane & 15);
    int cb = ccc * 32 + (lane >> 4) * 8;
    f16x8 pk;
#pragma unroll
    for (int j = 0; j < 8; ++j)
        pk[j] = (o < 18) ? (_Float16)w_off[(size_t)(o * C_ + cb + j) * 9 + k2] : (_Float16)0.f;
    *reinterpret_cast<f16x8*>(wfr + (size_t)idx * 8) = pk;
}

// ---------- offset conv via MFMA, no LDS ----------
__global__ __launch_bounds__(256) void k_offconv4(const _Float16* __restrict__ xT,
                                                  const _Float16* __restrict__ wofr,
                                                  const float* __restrict__ b_off,
                                                  float* __restrict__ offs) {
    int bh = blockIdx.x;
    int b = bh & 7, h = bh >> 3;
    int tid = threadIdx.x, lane = tid & 63, wm = tid >> 6;
    int px = wm * 16 + (lane & 15);
    int chl = (lane >> 4) * 8;
    f32x4 acc0 = (f32x4){0.f, 0.f, 0.f, 0.f};
    f32x4 acc1 = (f32x4){0.f, 0.f, 0.f, 0.f};
    const _Float16* xb = xT + (size_t)b * HW_ * C_;
    for (int k2 = 0; k2 < 9; ++k2) {
        int y = h + k2 / 3 - 1;
        int xs = px + k2 % 3 - 1;
        bool v = ((unsigned)y < 64u) && ((unsigned)xs < 64u);
        int yc = y < 0 ? 0 : (y > 63 ? 63 : y);
        int xc = xs < 0 ? 0 : (xs > 63 ? 63 : xs);
        const _Float16* xp = xb + (size_t)(yc * 64 + xc) * C_ + chl;
#pragma unroll
        for (int q = 0; q < 8; ++q) {
            f16x8 bf = *reinterpret_cast<const f16x8*>(xp + q * 32);
            if (!v) bf = (f16x8)(_Float16)0.f;
            const f16x8* wp = reinterpret_cast<const f16x8*>(wofr) +
                              (size_t)((k2 * 8 + q) * 2) * 64 + lane;
            acc0 = __builtin_amdgcn_mfma_f32_16x16x32_f16(wp[0], bf, acc0, 0, 0, 0);
            acc1 = __builtin_amdgcn_mfma_f32_16x16x32_f16(wp[64], bf, acc1, 0, 0, 0);
        }
    }
#pragma unroll
    for (int r = 0; r < 4; ++r) {
        int oc = (lane >> 4) * 4 + r;
        offs[(((size_t)b * 18 + oc) * 64 + h) * 64 + px] = acc0[r] + b_off[oc];
    }
#pragma unroll
    for (int r = 0; r < 4; ++r) {
        int oc = 16 + (lane >> 4) * 4 + r;
        if (oc < 18)
            offs[(((size_t)b * 18 + oc) * 64 + h) * 64 + px] = acc1[r] + b_off[oc];
    }
}

// ---------- deform v14: producer/consumer wave specialization (T16) ----------
// 512 threads: waves 0-3 = producers (pack only), waves 4-7 = consumers (MFMA only).
// Producers pack step s+1 while consumers MFMA step s. s_samp triple-buffered.
__global__ __launch_bounds__(512, 4) void k_deform14(const _Float16* __restrict__ xT,
                                                     const _Float16* __restrict__ wfrag,
                                                     const float* __restrict__ offs,
                                                     float* __restrict__ out) {
    int blk = blockIdx.x;
    int b = blk & 7, h = blk >> 3;
    int tid = threadIdx.x, lane = tid & 63, wid = tid >> 6;

    __shared__ uint4 s_geo[576];
    __shared__ __align__(16) _Float16 s_x[2][5 * RS];      // 5-row windows, double-buffered
    __shared__ __align__(16) _Float16 s_samp[3][64 * 40];  // triple buffer

    const _Float16* xb = xT + (size_t)b * HW_ * C_;

    // producer roles (tid < 256): pixel gp, octet gq; stage roles spx/so
    int gp = tid & 63, gq = (tid >> 6) & 3;
    int spx = (tid & 255) >> 2, so = tid & 3;
    f16x8 st[5];
#define STAGE_LOAD(CQ)                                                             \
    {                                                                              \
        _Pragma("unroll") for (int r = 0; r < 5; ++r)                              \
        {                                                                          \
            int yr = h - 2 + r;                                                    \
            yr = yr < 0 ? 0 : (yr > 63 ? 63 : yr);                                 \
            st[r] = *reinterpret_cast<const f16x8*>(                               \
                xb + (size_t)(yr * 64 + spx) * C_ + (CQ) * 32 + so * 8);           \
        }                                                                          \
    }
#define STAGE_WRITE(PAR)                                                           \
    {                                                                              \
        _Pragma("unroll") for (int r = 0; r < 5; ++r)                              \
            *reinterpret_cast<f16x8*>(&s_x[PAR][r * RS + spx * 40 + so * 8]) = st[r]; \
    }

    bool is_prod = (wid < 4);

    if (is_prod) STAGE_LOAD(0);

    // ---- geometry (all threads; 5-row window flag in [0,3]) ----
    for (int idx = tid; idx < 576; idx += 512) {
        int k2 = idx >> 6, p = idx & 63;
        float dy = offs[(((size_t)b * 18 + k2 * 2 + 0) * 64 + h) * 64 + p];
        float dx = offs[(((size_t)b * 18 + k2 * 2 + 1) * 64 + h) * 64 + p];
        float py = (float)(h - 1 + k2 / 3) + dy;
        float pxx = (float)(p - 1 + k2 % 3) + dx;
        float y0f = floorf(py), x0f = floorf(pxx);
        float wy = py - y0f, wx = pxx - x0f;
        int y0 = (int)y0f, x0 = (int)x0f;
        float w00 = (1.f - wy) * (1.f - wx), w01 = (1.f - wy) * wx;
        float w10 = wy * (1.f - wx), w11 = wy * wx;
        bool vy0 = (unsigned)y0 < 64u, vy1 = (unsigned)(y0 + 1) < 64u;
        bool vx0 = (unsigned)x0 < 64u, vx1 = (unsigned)(x0 + 1) < 64u;
        if (!(vy0 && vx0)) w00 = 0.f;
        if (!(vy0 && vx1)) w01 = 0.f;
        if (!(vy1 && vx0)) w10 = 0.f;
        if (!(vy1 && vx1)) w11 = 0.f;
        union { _Float16 h2[2]; unsigned u; } p01, p23;
        p01.h2[0] = (_Float16)w00; p01.h2[1] = (_Float16)w01;
        p23.h2[0] = (_Float16)w10; p23.h2[1] = (_Float16)w11;
        int x0c = x0 < 0 ? 0 : (x0 > 63 ? 63 : x0);
        int x1c = (x0 + 1) < 0 ? 0 : ((x0 + 1) > 63 ? 63 : (x0 + 1));
        int y0c = y0 < 0 ? 0 : (y0 > 63 ? 63 : y0);
        int y1c = (y0 + 1) < 0 ? 0 : ((y0 + 1) > 63 ? 63 : (y0 + 1));
        int ry0 = y0 - (h - 2);
        unsigned flag = (ry0 >= 0 && ry0 <= 3) ? (unsigned)ry0 : 255u;
        uint4 g;
        g.x = p01.u;
        g.y = p23.u;
        g.z = (unsigned)x0c | ((unsigned)x1c << 16);
        g.w = (unsigned)y0c | ((unsigned)y1c << 8) | (flag << 16);
        s_geo[idx] = g;
    }

    if (is_prod) STAGE_WRITE(0);
    asm volatile("s_waitcnt lgkmcnt(0)" ::: "memory");
    __builtin_amdgcn_s_barrier();

#define PACKSTEP(T, BUF)                                                           \
    {                                                                              \
        int t_ = (T);                                                              \
        int cqt_ = t_ / 9, k2t_ = t_ - cqt_ * 9;                                   \
        uint4 gg = s_geo[k2t_ * 64 + gp];                                          \
        union { unsigned u; _Float16 h2[2]; } p01, p23;                            \
        p01.u = gg.x; p23.u = gg.y;                                                \
        int x0c = gg.z & 0xFFFF, x1c = gg.z >> 16;                                 \
        int flag = gg.w >> 16;                                                     \
        f16x8 c00, c01, c10, c11;                                                  \
        if (flag <= 3) {                                                           \
            const _Float16* b0 = &s_x[cqt_ & 1][flag * RS + gq * 8];               \
            c00 = *reinterpret_cast<const f16x8*>(b0 + x0c * 40);                  \
            c01 = *reinterpret_cast<const f16x8*>(b0 + x1c * 40);                  \
            c10 = *reinterpret_cast<const f16x8*>(b0 + RS + x0c * 40);             \
            c11 = *reinterpret_cast<const f16x8*>(b0 + RS + x1c * 40);             \
        } else {                                                                   \
            int y0c = gg.w & 0xFF, y1c = (gg.w >> 8) & 0xFF;                       \
            const _Float16* gb = xb + cqt_ * 32 + gq * 8;                          \
            c00 = *reinterpret_cast<const f16x8*>(gb + (size_t)(y0c * 64 + x0c) * C_); \
            c01 = *reinterpret_cast<const f16x8*>(gb + (size_t)(y0c * 64 + x1c) * C_); \
            c10 = *reinterpret_cast<const f16x8*>(gb + (size_t)(y1c * 64 + x0c) * C_); \
            c11 = *reinterpret_cast<const f16x8*>(gb + (size_t)(y1c * 64 + x1c) * C_); \
        }                                                                          \
        f16x8 pk = c00 * p01.h2[0] + c01 * p01.h2[1] + c10 * p23.h2[0] + c11 * p23.h2[1]; \
        *reinterpret_cast<f16x8*>(&s_samp[BUF][gp * 40 + gq * 8]) = pk;            \
    }

    if (is_prod) {
        // prologue pack step 0 into buf 0
        PACKSTEP(0, 0);
        asm volatile("s_waitcnt lgkmcnt(0)" ::: "memory");
        __builtin_amdgcn_s_barrier();  // barrier #0

        // interval s (=t-1) packs step t into buf t%3
#pragma unroll 1
        for (int t = 1; t < 72; ++t) {
            int cqt = t / 9, k2t = t - cqt * 9;
            if (k2t == 1 && cqt < 7) STAGE_LOAD(cqt + 1);
            if (k2t == 7 && cqt < 7) STAGE_WRITE((cqt + 1) & 1);
            PACKSTEP(t, t % 3);
            asm volatile("s_waitcnt lgkmcnt(0)" ::: "memory");
            __builtin_amdgcn_s_barrier();
        }
        __builtin_amdgcn_s_barrier();  // final interval (consumers' step 71)
    } else {
        int wc = wid - 4;  // consumer wave: M-rows [wc*64, +64)
        f32x4 acc[4][4];
#pragma unroll
        for (int i = 0; i < 4; ++i)
#pragma unroll
            for (int j = 0; j < 4; ++j) acc[i][j] = (f32x4){0.f, 0.f, 0.f, 0.f};

        __builtin_amdgcn_s_barrier();  // barrier #0: buf0 ready
        __builtin_amdgcn_sched_barrier(0);

#pragma unroll 1
        for (int s = 0; s < 72; ++s) {
            int cq = s / 9, k2 = s - cq * 9;
            f16x8 Ac[4];
            const f16x8* wf = reinterpret_cast<const f16x8*>(wfrag) +
                              ((size_t)((k2 * 8 + cq) * 16) + wc * 4) * 64 + lane;
#pragma unroll
            for (int mf = 0; mf < 4; ++mf) Ac[mf] = wf[(size_t)mf * 64];

            const _Float16* sb = s_samp[s % 3];
            f16x8 bfr[4];
#pragma unroll
            for (int nf = 0; nf < 4; ++nf) {
                int n = nf * 16 + (lane & 15);
                bfr[nf] = *reinterpret_cast<const f16x8*>(&sb[n * 40 + (lane >> 4) * 8]);
            }
#pragma unroll
            for (int mf = 0; mf < 4; ++mf)
#pragma unroll
                for (int nf = 0; nf < 4; ++nf)
                    acc[mf][nf] = __builtin_amdgcn_mfma_f32_16x16x32_f16(
                        Ac[mf], bfr[nf], acc[mf][nf], 0, 0, 0);

            __builtin_amdgcn_s_barrier();
            __builtin_amdgcn_sched_barrier(0);
        }

        float* op = out + (size_t)b * O_ * HW_ + h * 64;
#pragma unroll
        for (int mf = 0; mf < 4; ++mf)
#pragma unroll
            for (int nf = 0; nf < 4; ++nf)
#pragma unroll
                for (int r = 0; r < 4; ++r) {
                    int o = wc * 64 + mf * 16 + (lane >> 4) * 4 + r;
                    int w = nf * 16 + (lane & 15);
                    op[(size_t)o * HW_ + w] = acc[mf][nf][r];
                }
    }
}

extern "C" void kernel_launch(void* const* d_in, const int* in_sizes, int n_in,
                              void* d_out, int out_size, void* d_ws, size_t ws_size,
                              hipStream_t stream) {
    const float* x = (const float*)d_in[0];
    const float* w_off = (const float*)d_in[1];
    const float* b_off = (const float*)d_in[2];
    const float* w_def = (const float*)d_in[3];
    float* out = (float*)d_out;
    char* ws = (char*)d_ws;

    float* offs = (float*)ws;                                            // 2,359,296 B
    _Float16* xT = (_Float16*)(ws + 2359296);                            // 16,777,216 B
    _Float16* wfrag = (_Float16*)(ws + 2359296 + 16777216);              // 1,179,648 B
    _Float16* wofr = (_Float16*)(ws + 2359296 + 16777216 + 1179648);     // 147,456 B

    k_nhwc2<<<512, 256, 0, stream>>>(x, xT);
    k_prep_wdef<<<288, 256, 0, stream>>>(w_def, wfrag);
    k_prep_woffrag<<<36, 256, 0, stream>>>(w_off, wofr);
    k_offconv4<<<512, 256, 0, stream>>>(xT, wofr, b_off, offs);
    k_deform14<<<512, 512, 0, stream>>>(xT, wfrag, offs, out);
}